// Round 1
// baseline (168.405 us; speedup 1.0000x reference)
//
#include <hip/hip_runtime.h>
#include <stdint.h>

typedef __attribute__((ext_vector_type(8))) short short8;       // 8 x bf16
typedef __attribute__((ext_vector_type(4))) float f32x4;
typedef __attribute__((ext_vector_type(4))) unsigned short ushort4_;

#define MFMA16(a, b, c) __builtin_amdgcn_mfma_f32_16x16x32_bf16((a), (b), (c), 0, 0, 0)

static __device__ __forceinline__ unsigned short f2bf(float f) {
    unsigned u = __float_as_uint(f);
    u += 0x7fffu + ((u >> 16) & 1u);   // round-to-nearest-even
    return (unsigned short)(u >> 16);
}

static __device__ __forceinline__ float exp2_fast(float x) {
#if __has_builtin(__builtin_amdgcn_exp2f)
    return __builtin_amdgcn_exp2f(x);
#else
    return exp2f(x);
#endif
}

// ---------------------------------------------------------------------------
// Kernel 1: QKV projection.  C = X[8192,1024] @ W[128,1024]^T  -> [8192,128]
//   head 0: Q, scaled by log2(e)/sqrt(128), bf16
//   head 1: K, bf16
//   head 2: V, stored TRANSPOSED as Vt[128][8192] bf16
// 128-row M-tile per block, BK=64, f32->bf16 conversion during staging.
// ---------------------------------------------------------------------------
__global__ __launch_bounds__(256) void qkv_kernel(
    const float* __restrict__ X,
    const float* __restrict__ Wq, const float* __restrict__ Wk, const float* __restrict__ Wv,
    unsigned short* __restrict__ Qs, unsigned short* __restrict__ Kb, unsigned short* __restrict__ Vt)
{
    __shared__ __align__(16) char lds[32768];   // X tile 16KB @0, W tile 16KB @16384
    const int tid  = threadIdx.x;
    const int lane = tid & 63, wid = tid >> 6;
    const int m0   = blockIdx.x * 128;
    const int hd   = blockIdx.y;
    const float* W = (hd == 0) ? Wq : ((hd == 1) ? Wk : Wv);

    f32x4 acc[2][8];
#pragma unroll
    for (int a = 0; a < 2; a++)
#pragma unroll
        for (int b = 0; b < 8; b++) acc[a][b] = (f32x4)0.0f;

    const int srow  = tid >> 1;            // 0..127 (tile row for staging)
    const int shalf = (tid & 1) * 32;      // k-offset (elements)
    const int lrow  = lane & 15, lgrp = lane >> 4;

    for (int ks = 0; ks < 1024; ks += 64) {
        const float* xsrc = X + (size_t)(m0 + srow) * 1024 + ks + shalf;
        const float* wsrc = W + (size_t)srow * 1024 + ks + shalf;
        const int sw = (srow & 7) << 4;
#pragma unroll
        for (int i = 0; i < 8; ++i) {
            f32x4 xv = *(const f32x4*)(xsrc + i * 4);
            f32x4 wv = *(const f32x4*)(wsrc + i * 4);
            ushort4_ xb, wb;
#pragma unroll
            for (int j = 0; j < 4; j++) { xb[j] = f2bf(xv[j]); wb[j] = f2bf(wv[j]); }
            const int kb = (shalf + i * 4) * 2;   // byte offset within 128B row
            *(ushort4_*)(lds + srow * 128 + (kb ^ sw))         = xb;
            *(ushort4_*)(lds + 16384 + srow * 128 + (kb ^ sw)) = wb;
        }
        __syncthreads();
#pragma unroll
        for (int kc = 0; kc < 2; ++kc) {
            const int koff = (kc * 32 + lgrp * 8) * 2;   // byte offset in row
            const int r0 = wid * 32 + lrow;
            const int r1 = wid * 32 + 16 + lrow;
            short8 a0 = *(const short8*)(lds + r0 * 128 + (koff ^ ((r0 & 7) << 4)));
            short8 a1 = *(const short8*)(lds + r1 * 128 + (koff ^ ((r1 & 7) << 4)));
#pragma unroll
            for (int cf = 0; cf < 8; ++cf) {
                const int n = cf * 16 + lrow;
                short8 bf = *(const short8*)(lds + 16384 + n * 128 + (koff ^ ((n & 7) << 4)));
                acc[0][cf] = MFMA16(a0, bf, acc[0][cf]);
                acc[1][cf] = MFMA16(a1, bf, acc[1][cf]);
            }
        }
        __syncthreads();
    }

    // epilogue: C/D layout col=lane&15, row=(lane>>4)*4+reg  [m89-verified]
    const float qscale = 0.12752039f;   // log2(e)/sqrt(128)
    if (hd < 2) {
        unsigned short* dst = (hd == 0) ? Qs : Kb;
        const float sc = (hd == 0) ? qscale : 1.0f;
#pragma unroll
        for (int rf = 0; rf < 2; ++rf)
#pragma unroll
            for (int cf = 0; cf < 8; ++cf)
#pragma unroll
                for (int r = 0; r < 4; ++r) {
                    const int row = m0 + wid * 32 + rf * 16 + lgrp * 4 + r;
                    const int col = cf * 16 + lrow;
                    dst[(size_t)row * 128 + col] = f2bf(acc[rf][cf][r] * sc);
                }
    } else {
#pragma unroll
        for (int rf = 0; rf < 2; ++rf)
#pragma unroll
            for (int cf = 0; cf < 8; ++cf) {
                const int row0 = m0 + wid * 32 + rf * 16 + lgrp * 4;
                const int col  = cf * 16 + lrow;
                ushort4_ v;
#pragma unroll
                for (int r = 0; r < 4; r++) v[r] = f2bf(acc[rf][cf][r]);
                *(ushort4_*)(Vt + (size_t)col * 8192 + row0) = v;   // 4 consecutive rows -> 8B store
            }
    }
}

// ---------------------------------------------------------------------------
// Kernel 2: flash attention.
// Block = 512 threads = 8 waves: (2 q-subtiles of 16 rows) x (4 KV quarters).
// Each wave: 16 q-rows, iterates its 2048-kv quarter in KVBLK=64 tiles.
// K tiles [64][128]bf16 and Vt tiles [128][64]bf16 staged in LDS (XOR-swizzled).
// In-register online softmax (shfl over 16-lane groups); P -> wave-private LDS
// for C-layout -> A-layout conversion; 4-way merge via LDS at the end.
// ---------------------------------------------------------------------------
__global__ __launch_bounds__(512) void attn_kernel(
    const unsigned short* __restrict__ Qs,
    const unsigned short* __restrict__ Kb,
    const unsigned short* __restrict__ Vt,
    float* __restrict__ out)
{
    __shared__ __align__(16) char lds[147456];  // K[4]:0..64K, V[4]:64K..128K, P[8]:128K..144K
    const int tid  = threadIdx.x;
    const int lane = tid & 63, wid = tid >> 6;
    const int wq = wid & 1, wh = wid >> 1;      // q-subtile, kv-quarter
    const int lrow = lane & 15, lgrp = lane >> 4;
    const int q0 = blockIdx.x * 32;
    const int qb = q0 + wq * 16;

    // Q fragments (A operand): lane holds Q[qb+lrow][c*32 + lgrp*8 .. +8]
    short8 qf[4];
#pragma unroll
    for (int c = 0; c < 4; c++)
        qf[c] = *(const short8*)(Qs + (size_t)(qb + lrow) * 128 + c * 32 + lgrp * 8);

    f32x4 o[8];
#pragma unroll
    for (int i = 0; i < 8; i++) o[i] = (f32x4)0.0f;
    float m[4], l[4];
#pragma unroll
    for (int r = 0; r < 4; r++) { m[r] = -1e30f; l[r] = 0.0f; }

    char* Kq = lds + wh * 16384;
    char* Vq = lds + 65536 + wh * 16384;
    char* Pw = lds + 131072 + wid * 2048;
    const int psw = (lrow & 7) << 4;

    for (int it = 0; it < 32; ++it) {
        // ---- stage K quarters (64KB) then Vt quarters (64KB), reg-staged ----
#pragma unroll
        for (int j = 0; j < 8; ++j) {
            const int s = (j * 512 + tid) * 16;          // 0..65535
            const int h = s >> 14, c = s & 16383;
            const int kv = c >> 8, inner = c & 255;
            f32x4 v = *(const f32x4*)((const char*)Kb +
                        (size_t)(h * 2048 + it * 64 + kv) * 256 + inner);
            *(f32x4*)(lds + h * 16384 + kv * 256 + (inner ^ ((kv & 7) << 4))) = v;
        }
#pragma unroll
        for (int j = 0; j < 8; ++j) {
            const int s = (j * 512 + tid) * 16;
            const int h = s >> 14, c = s & 16383;
            const int d = c >> 7, inner = c & 127;
            f32x4 v = *(const f32x4*)((const char*)Vt +
                        (size_t)d * 16384 + (size_t)(h * 2048 + it * 64) * 2 + inner);
            *(f32x4*)(lds + 65536 + h * 16384 + d * 128 + (inner ^ ((d & 7) << 4))) = v;
        }
        __syncthreads();

        // ---- S = Q K^T (exp2 domain; scale folded into Q) ----
        f32x4 s4[4];
#pragma unroll
        for (int f = 0; f < 4; ++f) {
            s4[f] = (f32x4)0.0f;
#pragma unroll
            for (int c = 0; c < 4; ++c) {
                const int kvr  = f * 16 + lrow;
                const int koff = (c * 32 + lgrp * 8) * 2;
                short8 bk = *(const short8*)(Kq + kvr * 256 + (koff ^ ((kvr & 7) << 4)));
                s4[f] = MFMA16(qf[c], bk, s4[f]);
            }
        }

        // ---- online softmax (row = lgrp*4 + r; reduce over l&15 lanes) ----
        float alpha[4];
#pragma unroll
        for (int r = 0; r < 4; ++r) {
            float tm = fmaxf(fmaxf(s4[0][r], s4[1][r]), fmaxf(s4[2][r], s4[3][r]));
            tm = fmaxf(tm, __shfl_xor(tm, 1));
            tm = fmaxf(tm, __shfl_xor(tm, 2));
            tm = fmaxf(tm, __shfl_xor(tm, 4));
            tm = fmaxf(tm, __shfl_xor(tm, 8));
            const float mn = fmaxf(m[r], tm);
            alpha[r] = exp2_fast(m[r] - mn);
            m[r] = mn;
            float rs = 0.f;
#pragma unroll
            for (int f = 0; f < 4; ++f) {
                const float p = exp2_fast(s4[f][r] - mn);
                s4[f][r] = p;
                rs += p;
            }
            rs += __shfl_xor(rs, 1);
            rs += __shfl_xor(rs, 2);
            rs += __shfl_xor(rs, 4);
            rs += __shfl_xor(rs, 8);
            l[r] = l[r] * alpha[r] + rs;
#pragma unroll
            for (int df = 0; df < 8; ++df) o[df][r] *= alpha[r];
        }

        // ---- P (C layout) -> wave-private LDS (bf16, swizzled) ----
#pragma unroll
        for (int f = 0; f < 4; ++f)
#pragma unroll
            for (int r = 0; r < 4; ++r) {
                const int qr  = lgrp * 4 + r;
                const int kvb = (f * 16 + lrow) * 2;
                *(unsigned short*)(Pw + qr * 128 + (kvb ^ ((qr & 7) << 4))) = f2bf(s4[f][r]);
            }

        // ---- O += P V ----
#pragma unroll
        for (int kc = 0; kc < 2; ++kc) {
            const int koff = kc * 64 + lgrp * 16;
            short8 pa = *(const short8*)(Pw + lrow * 128 + (koff ^ psw));
#pragma unroll
            for (int df = 0; df < 8; ++df) {
                const int d = df * 16 + lrow;
                short8 vb = *(const short8*)(Vq + d * 128 + (koff ^ ((d & 7) << 4)));
                o[df] = MFMA16(pa, vb, o[df]);
            }
        }
        __syncthreads();
    }

    // ---- 4-way merge across kv quarters (LDS reuses K/V region) ----
    if (wh != 0) {
        char* mb = lds + ((wh - 1) * 2 + wq) * 8320;   // 8KB O + 128B (m,l)
#pragma unroll
        for (int df = 0; df < 8; ++df)
#pragma unroll
            for (int r = 0; r < 4; ++r) {
                const int row = lgrp * 4 + r;
                *(float*)(mb + row * 512 + (df * 16 + lrow) * 4) = o[df][r];
            }
        if (lrow == 0) {
#pragma unroll
            for (int r = 0; r < 4; ++r) {
                const int row = lgrp * 4 + r;
                *(float*)(mb + 8192 + row * 8)     = m[r];
                *(float*)(mb + 8192 + row * 8 + 4) = l[r];
            }
        }
    }
    __syncthreads();
    if (wh == 0) {
#pragma unroll
        for (int h = 0; h < 3; ++h) {
            char* mb = lds + (h * 2 + wq) * 8320;
#pragma unroll
            for (int r = 0; r < 4; ++r) {
                const int row = lgrp * 4 + r;
                const float pm = *(float*)(mb + 8192 + row * 8);
                const float pl = *(float*)(mb + 8192 + row * 8 + 4);
                const float M = fmaxf(m[r], pm);
                const float a = exp2_fast(m[r] - M);
                const float b = exp2_fast(pm - M);
                l[r] = l[r] * a + pl * b;
                m[r] = M;
#pragma unroll
                for (int df = 0; df < 8; ++df) {
                    const float po = *(float*)(mb + row * 512 + (df * 16 + lrow) * 4);
                    o[df][r] = o[df][r] * a + po * b;
                }
            }
        }
#pragma unroll
        for (int r = 0; r < 4; ++r) {
            const float inv = 1.0f / l[r];
            const int row = qb + lgrp * 4 + r;
#pragma unroll
            for (int df = 0; df < 8; ++df)
                out[(size_t)row * 128 + df * 16 + lrow] = o[df][r] * inv;
        }
    }
}

extern "C" void kernel_launch(void* const* d_in, const int* in_sizes, int n_in,
                              void* d_out, int out_size, void* d_ws, size_t ws_size,
                              hipStream_t stream)
{
    const float* X  = (const float*)d_in[0];
    const float* Wq = (const float*)d_in[1];
    const float* Wk = (const float*)d_in[2];
    const float* Wv = (const float*)d_in[3];

    unsigned short* Qs = (unsigned short*)d_ws;                 // [8192][128] bf16 (pre-scaled)
    unsigned short* Kb = Qs + (size_t)8192 * 128;               // [8192][128] bf16
    unsigned short* Vt = Kb + (size_t)8192 * 128;               // [128][8192] bf16 (transposed)
    float* out = (float*)d_out;

    qkv_kernel<<<dim3(64, 3), 256, 0, stream>>>(X, Wq, Wk, Wv, Qs, Kb, Vt);
    attn_kernel<<<dim3(256), 512, 0, stream>>>(Qs, Kb, Vt, out);
}

// Round 2
// 108.894 us; speedup vs baseline: 1.5465x; 1.5465x over previous
//
#include <hip/hip_runtime.h>
#include <stdint.h>

typedef __attribute__((ext_vector_type(8))) short short8;       // 8 x bf16
typedef __attribute__((ext_vector_type(4))) float f32x4;
typedef __attribute__((ext_vector_type(4))) unsigned short ushort4_;
typedef __attribute__((ext_vector_type(4))) unsigned int uint4_;

#define MFMA16(a, b, c) __builtin_amdgcn_mfma_f32_16x16x32_bf16((a), (b), (c), 0, 0, 0)

static __device__ __forceinline__ unsigned short f2bf(float f) {
    unsigned u = __float_as_uint(f);
    u += 0x7fffu + ((u >> 16) & 1u);   // RNE
    return (unsigned short)(u >> 16);
}

static __device__ __forceinline__ float exp2_fast(float x) {
#if __has_builtin(__builtin_amdgcn_exp2f)
    return __builtin_amdgcn_exp2f(x);
#else
    return exp2f(x);
#endif
}

static __device__ __forceinline__ unsigned cvt_pk(float lo, float hi) {
    unsigned r;
    asm("v_cvt_pk_bf16_f32 %0, %1, %2" : "=v"(r) : "v"(lo), "v"(hi));
    return r;
}

static __device__ __forceinline__ short8 pack8(float a0, float a1, float a2, float a3,
                                               float a4, float a5, float a6, float a7) {
    union { uint4_ u; short8 s; } c;
    c.u[0] = cvt_pk(a0, a1); c.u[1] = cvt_pk(a2, a3);
    c.u[2] = cvt_pk(a4, a5); c.u[3] = cvt_pk(a6, a7);
    return c.s;
}

// ---------------------------------------------------------------------------
// Kernel 0: W (3 heads, f32) -> bf16, contiguous Wb[3][128][1024]
// ---------------------------------------------------------------------------
__global__ __launch_bounds__(256) void wcvt_kernel(
    const float* __restrict__ Wq, const float* __restrict__ Wk, const float* __restrict__ Wv,
    unsigned short* __restrict__ Wb)
{
    const int hd = blockIdx.y;
    const float* W = (hd == 0) ? Wq : ((hd == 1) ? Wk : Wv);
    const int idx = (blockIdx.x * 256 + threadIdx.x) * 4;   // 128 blocks * 256 * 4 = 131072
    f32x4 v = *(const f32x4*)(W + idx);
    ushort4_ o;
#pragma unroll
    for (int j = 0; j < 4; ++j) o[j] = f2bf(v[j]);
    *(ushort4_*)(Wb + (size_t)hd * 131072 + idx) = o;
}

// ---------------------------------------------------------------------------
// Kernel 1: QKV projection. M-tile 64, 4 waves, W already bf16.
//   head 0: Q scaled by log2(e)/sqrt(128); head 1: K; head 2: V -> Vt[128][8192]
// ---------------------------------------------------------------------------
__global__ __launch_bounds__(256) void qkv_kernel(
    const float* __restrict__ X, const unsigned short* __restrict__ Wb,
    unsigned short* __restrict__ Qs, unsigned short* __restrict__ Kb, unsigned short* __restrict__ Vt)
{
    __shared__ __align__(16) char lds[24576];   // X bf16 8KB @0, W bf16 16KB @8192
    const int tid  = threadIdx.x;
    const int lane = tid & 63, wid = tid >> 6;
    const int lrow = lane & 15, lgrp = lane >> 4;
    const int m0   = blockIdx.x * 64;
    const int hd   = blockIdx.y;
    const unsigned short* W = Wb + (size_t)hd * 131072;

    f32x4 acc[8];
#pragma unroll
    for (int b = 0; b < 8; b++) acc[b] = (f32x4)0.0f;

    const int xrow = tid >> 2, xseg = tid & 3;   // X: 64 rows, 16 f32/thread
    const int wrow = tid >> 1, whalf = tid & 1;  // W: 128 rows, 64 bf16/thread

    for (int ks = 0; ks < 1024; ks += 64) {
        const float* xsrc = X + (size_t)(m0 + xrow) * 1024 + ks + xseg * 16;
        f32x4 x0 = *(const f32x4*)(xsrc);
        f32x4 x1 = *(const f32x4*)(xsrc + 4);
        f32x4 x2 = *(const f32x4*)(xsrc + 8);
        f32x4 x3 = *(const f32x4*)(xsrc + 12);
        const unsigned short* wsrc = W + (size_t)wrow * 1024 + ks + whalf * 32;
        short8 w0 = *(const short8*)(wsrc);
        short8 w1 = *(const short8*)(wsrc + 8);
        short8 w2 = *(const short8*)(wsrc + 16);
        short8 w3 = *(const short8*)(wsrc + 24);

        const int swx = (xrow & 7) << 4;
        short8 px0 = pack8(x0[0], x0[1], x0[2], x0[3], x1[0], x1[1], x1[2], x1[3]);
        short8 px1 = pack8(x2[0], x2[1], x2[2], x2[3], x3[0], x3[1], x3[2], x3[3]);
        *(short8*)(lds + xrow * 128 + ((xseg * 32)      ^ swx)) = px0;
        *(short8*)(lds + xrow * 128 + ((xseg * 32 + 16) ^ swx)) = px1;
        const int sww = (wrow & 7) << 4;
        *(short8*)(lds + 8192 + wrow * 128 + ((whalf * 64)      ^ sww)) = w0;
        *(short8*)(lds + 8192 + wrow * 128 + ((whalf * 64 + 16) ^ sww)) = w1;
        *(short8*)(lds + 8192 + wrow * 128 + ((whalf * 64 + 32) ^ sww)) = w2;
        *(short8*)(lds + 8192 + wrow * 128 + ((whalf * 64 + 48) ^ sww)) = w3;
        __syncthreads();

#pragma unroll
        for (int kc = 0; kc < 2; ++kc) {
            const int r0 = wid * 16 + lrow;
            const int koff = kc * 64 + lgrp * 16;
            short8 a0 = *(const short8*)(lds + r0 * 128 + (koff ^ ((r0 & 7) << 4)));
#pragma unroll
            for (int cf = 0; cf < 8; ++cf) {
                const int n = cf * 16 + lrow;
                short8 bf = *(const short8*)(lds + 8192 + n * 128 + (koff ^ ((n & 7) << 4)));
                acc[cf] = MFMA16(a0, bf, acc[cf]);
            }
        }
        __syncthreads();
    }

    const float qscale = 0.12752039f;   // log2(e)/sqrt(128)
    if (hd < 2) {
        unsigned short* dst = (hd == 0) ? Qs : Kb;
        const float sc = (hd == 0) ? qscale : 1.0f;
#pragma unroll
        for (int cf = 0; cf < 8; ++cf)
#pragma unroll
            for (int r = 0; r < 4; ++r) {
                const int row = m0 + wid * 16 + lgrp * 4 + r;
                const int col = cf * 16 + lrow;
                dst[(size_t)row * 128 + col] = f2bf(acc[cf][r] * sc);
            }
    } else {
#pragma unroll
        for (int cf = 0; cf < 8; ++cf) {
            const int row0 = m0 + wid * 16 + lgrp * 4;
            const int col  = cf * 16 + lrow;
            ushort4_ v;
#pragma unroll
            for (int r = 0; r < 4; r++) v[r] = f2bf(acc[cf][r]);
            *(ushort4_*)(Vt + (size_t)col * 8192 + row0) = v;
        }
    }
}

// ---------------------------------------------------------------------------
// Kernel 2: flash-attention partial.
// grid 256 = 128 q-tiles(64 rows) x 2 kv-splits(4096). Block: 8 waves =
// 2 q-halves(32 rows) x 4 kv-lanes(1024 each). KVBLK=32, LDS double-buffered.
// Swapped QK (mfma(K,Q)) + sigma-permuted K rows => P pack is pure cvt_pk.
// Writes unnormalized partial O + (m,l) per row to workspace.
// ---------------------------------------------------------------------------
__global__ __launch_bounds__(512) void attn_kernel(
    const unsigned short* __restrict__ Qs,
    const unsigned short* __restrict__ Kb,
    const unsigned short* __restrict__ Vt,
    float* __restrict__ partO, float* __restrict__ partML)
{
    __shared__ __align__(16) char lds[131072];  // K dbuf 64KB @0, V dbuf 64KB @65536
    const int tid  = threadIdx.x;
    const int lane = tid & 63, wid = tid >> 6;
    const int lrow = lane & 15, lgrp = lane >> 4;
    const int kvlane = wid & 3, qh = wid >> 2;
    const int qtile = blockIdx.x >> 1, sp = blockIdx.x & 1;
    const int qb = qtile * 64 + qh * 32;
    const int kvstart = sp * 4096 + kvlane * 1024;
    const int lt = qh * 64 + lane;               // 0..127 within kv-lane pair

    // staging geometry
    const int krow = lt >> 2, kc0 = lt & 3;      // K: 32 rows x 256B, 4x16B chunks/thread
    const int vd = lt;                            // V: 128 rows(d) x 64B, 4x16B/thread
    const int ksl = ((krow >> 2) & 1) * 16 + (krow >> 3) * 4 + (krow & 3);  // sigma(krow)
    const int ksw = (ksl & 7) << 4;
    const int vsw = (vd & 3) << 4;

    // Q fragments (B operand): lane holds Q[qb + j*16 + (lane&15)][c*32 + lgrp*8 ..]
    short8 qf[2][4];
#pragma unroll
    for (int j = 0; j < 2; ++j)
#pragma unroll
        for (int c = 0; c < 4; ++c)
            qf[j][c] = *(const short8*)(Qs + (size_t)(qb + j * 16 + lrow) * 128 + c * 32 + lgrp * 8);

    f32x4 o[2][8];
#pragma unroll
    for (int j = 0; j < 2; ++j)
#pragma unroll
        for (int i = 0; i < 8; i++) o[j][i] = (f32x4)0.0f;
    float m[2] = { -1e30f, -1e30f }, l[2] = { 0.0f, 0.0f };

#define LOADTILE(T)                                                                        \
    do {                                                                                   \
        const char* ksrc = (const char*)Kb + ((size_t)(kvstart + (T) * 32 + krow)) * 256 + kc0 * 16; \
        kr[0] = *(const short8*)(ksrc);        kr[1] = *(const short8*)(ksrc + 64);        \
        kr[2] = *(const short8*)(ksrc + 128);  kr[3] = *(const short8*)(ksrc + 192);       \
        const char* vsrc = (const char*)Vt + (size_t)vd * 16384 + ((size_t)(kvstart + (T) * 32)) * 2; \
        vr[0] = *(const short8*)(vsrc);        vr[1] = *(const short8*)(vsrc + 16);        \
        vr[2] = *(const short8*)(vsrc + 32);   vr[3] = *(const short8*)(vsrc + 48);        \
    } while (0)

#define WRITETILE(KB_, VB_)                                                                \
    do {                                                                                   \
        char* kdst = (KB_) + ksl * 256;                                                    \
        *(short8*)(kdst + ((kc0 * 16)       ^ ksw)) = kr[0];                               \
        *(short8*)(kdst + ((kc0 * 16 + 64)  ^ ksw)) = kr[1];                               \
        *(short8*)(kdst + ((kc0 * 16 + 128) ^ ksw)) = kr[2];                               \
        *(short8*)(kdst + ((kc0 * 16 + 192) ^ ksw)) = kr[3];                               \
        char* vdst = (VB_) + vd * 64;                                                      \
        *(short8*)(vdst + ((0)  ^ vsw)) = vr[0];  *(short8*)(vdst + ((16) ^ vsw)) = vr[1]; \
        *(short8*)(vdst + ((32) ^ vsw)) = vr[2];  *(short8*)(vdst + ((48) ^ vsw)) = vr[3]; \
    } while (0)

    {   // prologue: tile 0 -> buf 0
        short8 kr[4], vr[4];
        LOADTILE(0);
        WRITETILE(lds + (kvlane * 2) * 8192, lds + 65536 + (kvlane * 2) * 8192);
    }
    __syncthreads();

    int cur = 0;
    for (int t = 0; t < 32; ++t) {
        short8 kr[4], vr[4];
        if (t < 31) LOADTILE(t + 1);
        char* kb = lds + (kvlane * 2 + cur) * 8192;
        char* vb = lds + 65536 + (kvlane * 2 + cur) * 8192;

        // ---- S^T = K Q (exp2 domain) ----
        f32x4 s[2][2];
        s[0][0] = s[0][1] = s[1][0] = s[1][1] = (f32x4)0.0f;
#pragma unroll
        for (int f = 0; f < 2; ++f) {
            const int rc = f * 16 + lrow;
            const int rsw = (rc & 7) << 4;
#pragma unroll
            for (int c = 0; c < 4; ++c) {
                short8 kf = *(const short8*)(kb + rc * 256 + ((c * 64 + lgrp * 16) ^ rsw));
                s[0][f] = MFMA16(kf, qf[0][c], s[0][f]);
                s[1][f] = MFMA16(kf, qf[1][c], s[1][f]);
            }
        }

        // ---- online softmax: lane owns q = j*16 + (lane&15), kv = 8*lgrp + 4f + r ----
        float tm[2];
#pragma unroll
        for (int j = 0; j < 2; ++j) {
            float t0 = fmaxf(fmaxf(s[j][0][0], s[j][0][1]), fmaxf(s[j][0][2], s[j][0][3]));
            float t1 = fmaxf(fmaxf(s[j][1][0], s[j][1][1]), fmaxf(s[j][1][2], s[j][1][3]));
            float t2 = fmaxf(t0, t1);
            t2 = fmaxf(t2, __shfl_xor(t2, 16));
            t2 = fmaxf(t2, __shfl_xor(t2, 32));
            tm[j] = t2;
        }
        const bool need = (tm[0] > m[0] + 8.0f) || (tm[1] > m[1] + 8.0f);
        if (__any(need)) {   // rescale (deferred-max skips this most tiles)
#pragma unroll
            for (int j = 0; j < 2; ++j) {
                const float mn = fmaxf(m[j], tm[j]);
                const float al = exp2_fast(m[j] - mn);
                m[j] = mn;
                l[j] *= al;
#pragma unroll
                for (int r = 0; r < 4; ++r) {
                    const float ar = __shfl(al, lgrp * 4 + r);
#pragma unroll
                    for (int df = 0; df < 8; ++df) o[j][df][r] *= ar;
                }
            }
        }
        short8 pa[2];
#pragma unroll
        for (int j = 0; j < 2; ++j) {
            const float p0 = exp2_fast(s[j][0][0] - m[j]);
            const float p1 = exp2_fast(s[j][0][1] - m[j]);
            const float p2 = exp2_fast(s[j][0][2] - m[j]);
            const float p3 = exp2_fast(s[j][0][3] - m[j]);
            const float p4 = exp2_fast(s[j][1][0] - m[j]);
            const float p5 = exp2_fast(s[j][1][1] - m[j]);
            const float p6 = exp2_fast(s[j][1][2] - m[j]);
            const float p7 = exp2_fast(s[j][1][3] - m[j]);
            float rs = ((p0 + p1) + (p2 + p3)) + ((p4 + p5) + (p6 + p7));
            rs += __shfl_xor(rs, 16);
            rs += __shfl_xor(rs, 32);
            l[j] += rs;
            pa[j] = pack8(p0, p1, p2, p3, p4, p5, p6, p7);
        }

        // ---- O += P V ----
#pragma unroll
        for (int df = 0; df < 8; ++df) {
            const int d = df * 16 + lrow;
            short8 vf = *(const short8*)(vb + d * 64 + ((lgrp * 16) ^ ((d & 3) << 4)));
            o[0][df] = MFMA16(pa[0], vf, o[0][df]);
            o[1][df] = MFMA16(pa[1], vf, o[1][df]);
        }

        __syncthreads();
        if (t < 31) WRITETILE(lds + (kvlane * 2 + (cur ^ 1)) * 8192,
                              lds + 65536 + (kvlane * 2 + (cur ^ 1)) * 8192);
        __syncthreads();
        cur ^= 1;
    }

    // ---- convert own state to row form (row = j*16 + lgrp*4 + r) ----
    float mr[2][4], lr_[2][4];
#pragma unroll
    for (int j = 0; j < 2; ++j)
#pragma unroll
        for (int r = 0; r < 4; ++r) {
            mr[j][r]  = __shfl(m[j], lgrp * 4 + r);
            lr_[j][r] = __shfl(l[j], lgrp * 4 + r);
        }

    // ---- in-block 4-way kv merge (LDS reuses staging area) ----
    __syncthreads();
    if (kvlane != 0) {
        char* mb = lds + (qh * 3 + (kvlane - 1)) * 16640;   // 16KB O + 256B ml
#pragma unroll
        for (int j = 0; j < 2; ++j)
#pragma unroll
            for (int df = 0; df < 8; ++df)
#pragma unroll
                for (int r = 0; r < 4; ++r)
                    *(float*)(mb + (j * 16 + lgrp * 4 + r) * 512 + (df * 16 + lrow) * 4) = o[j][df][r];
        if (lgrp == 0) {
#pragma unroll
            for (int j = 0; j < 2; ++j) {
                *(float*)(mb + 16384 + (j * 16 + lrow) * 8)     = m[j];
                *(float*)(mb + 16384 + (j * 16 + lrow) * 8 + 4) = l[j];
            }
        }
    }
    __syncthreads();
    if (kvlane == 0) {
#pragma unroll
        for (int h = 0; h < 3; ++h) {
            char* mb = lds + (qh * 3 + h) * 16640;
#pragma unroll
            for (int j = 0; j < 2; ++j)
#pragma unroll
                for (int r = 0; r < 4; ++r) {
                    const int qrow = j * 16 + lgrp * 4 + r;
                    const float pm = *(float*)(mb + 16384 + qrow * 8);
                    const float pl = *(float*)(mb + 16384 + qrow * 8 + 4);
                    const float M = fmaxf(mr[j][r], pm);
                    const float a = exp2_fast(mr[j][r] - M);
                    const float b = exp2_fast(pm - M);
                    lr_[j][r] = lr_[j][r] * a + pl * b;
                    mr[j][r] = M;
#pragma unroll
                    for (int df = 0; df < 8; ++df) {
                        const float po = *(float*)(mb + qrow * 512 + (df * 16 + lrow) * 4);
                        o[j][df][r] = o[j][df][r] * a + po * b;
                    }
                }
        }
        // ---- write unnormalized partial + (m,l) ----
#pragma unroll
        for (int j = 0; j < 2; ++j)
#pragma unroll
            for (int df = 0; df < 8; ++df)
#pragma unroll
                for (int r = 0; r < 4; ++r) {
                    const int qg = qb + j * 16 + lgrp * 4 + r;
                    partO[((size_t)sp * 8192 + qg) * 128 + df * 16 + lrow] = o[j][df][r];
                }
        if (lrow == 0) {
#pragma unroll
            for (int j = 0; j < 2; ++j)
#pragma unroll
                for (int r = 0; r < 4; ++r) {
                    const int qg = qb + j * 16 + lgrp * 4 + r;
                    partML[((size_t)sp * 8192 + qg) * 2]     = mr[j][r];
                    partML[((size_t)sp * 8192 + qg) * 2 + 1] = lr_[j][r];
                }
        }
    }
#undef LOADTILE
#undef WRITETILE
}

// ---------------------------------------------------------------------------
// Kernel 3: merge the 2 kv-split partials and normalize.
// ---------------------------------------------------------------------------
__global__ __launch_bounds__(256) void merge_kernel(
    const float* __restrict__ partO, const float* __restrict__ partML, float* __restrict__ out)
{
    const int gid = blockIdx.x * 256 + threadIdx.x;   // 0..262143
    const int q = gid >> 5, dc = gid & 31;
    const float m0 = partML[q * 2],          l0 = partML[q * 2 + 1];
    const float m1 = partML[16384 + q * 2],  l1 = partML[16384 + q * 2 + 1];
    const float M = fmaxf(m0, m1);
    const float e0 = exp2_fast(m0 - M), e1 = exp2_fast(m1 - M);
    const float inv = 1.0f / (l0 * e0 + l1 * e1);
    f32x4 v0 = *(const f32x4*)(partO + (size_t)q * 128 + dc * 4);
    f32x4 v1 = *(const f32x4*)(partO + (size_t)8192 * 128 + (size_t)q * 128 + dc * 4);
    f32x4 r;
#pragma unroll
    for (int k = 0; k < 4; ++k) r[k] = (v0[k] * e0 + v1[k] * e1) * inv;
    *(f32x4*)(out + (size_t)q * 128 + dc * 4) = r;
}

extern "C" void kernel_launch(void* const* d_in, const int* in_sizes, int n_in,
                              void* d_out, int out_size, void* d_ws, size_t ws_size,
                              hipStream_t stream)
{
    const float* X  = (const float*)d_in[0];
    const float* Wq = (const float*)d_in[1];
    const float* Wk = (const float*)d_in[2];
    const float* Wv = (const float*)d_in[3];

    char* ws = (char*)d_ws;
    const size_t QS_OFF  = 0;                                   // 8192*128 bf16 = 2 MiB
    const size_t KB_OFF  = QS_OFF + (size_t)8192 * 128 * 2;     // 2 MiB
    const size_t VT_OFF  = KB_OFF + (size_t)8192 * 128 * 2;     // 2 MiB (transposed V)
    const size_t WB_OFF  = VT_OFF + (size_t)8192 * 128 * 2;     // 3*128*1024 bf16 = 768 KiB
    const size_t PO_OFF  = WB_OFF + (size_t)3 * 128 * 1024 * 2; // 2*8192*128 f32 = 8 MiB
    const size_t PML_OFF = PO_OFF + (size_t)2 * 8192 * 128 * 4; // 2*8192*2 f32 = 128 KiB

    unsigned short* Qs  = (unsigned short*)(ws + QS_OFF);
    unsigned short* Kb  = (unsigned short*)(ws + KB_OFF);
    unsigned short* Vt  = (unsigned short*)(ws + VT_OFF);
    unsigned short* Wb  = (unsigned short*)(ws + WB_OFF);
    float* partO  = (float*)(ws + PO_OFF);
    float* partML = (float*)(ws + PML_OFF);
    float* out = (float*)d_out;

    wcvt_kernel<<<dim3(128, 3), 256, 0, stream>>>(Wq, Wk, Wv, Wb);
    qkv_kernel<<<dim3(128, 3), 256, 0, stream>>>(X, Wb, Qs, Kb, Vt);
    attn_kernel<<<dim3(256), 512, 0, stream>>>(Qs, Kb, Vt, partO, partML);
    merge_kernel<<<dim3(1024), 256, 0, stream>>>(partO, partML, out);
}